// Round 8
// baseline (322.502 us; speedup 1.0000x reference)
//
#include <hip/hip_runtime.h>

#define F_IN  512
#define F_OUT 128
#define CB    128          // nodes per coarse bucket
#define EPB   4096         // edges per partition block
#define CMAX  512          // max coarse buckets (N <= 65536)
#define CAP   4096         // max edges per half-bucket in LDS (mean 2048)

typedef __attribute__((ext_vector_type(8))) short  short8;
typedef __attribute__((ext_vector_type(4))) float  floatx4;

__device__ __forceinline__ unsigned short f2bf(float f) {
    unsigned u = __float_as_uint(f);
    return (unsigned short)((u + 0x7FFF + ((u >> 16) & 1)) >> 16);  // RNE
}
__device__ __forceinline__ float bf2f(unsigned b) {
    return __uint_as_float(b << 16);
}
// pack two fp32 -> two bf16 (round-half-up): 2 adds + 1 v_perm
__device__ __forceinline__ unsigned pack2bf(float lo, float hi) {
    return __builtin_amdgcn_perm(__float_as_uint(hi) + 0x8000u,
                                 __float_as_uint(lo) + 0x8000u, 0x07060302u);
}

// ---------------------------------------------------------------------------
// GEMM, barrier-free / LDS-free: each wave owns 16 rows exclusively (N=128
// output cols = 8 MFMA n-tiles per wave), so x has no cross-wave reuse and
// wt (128 KB bf16) is L2-resident. A: global fp32 -> pack bf16 in VALU.
// B: global 16B loads served by L2. mfma_f32_16x16x32_bf16.
// ---------------------------------------------------------------------------
__global__ __launch_bounds__(256, 3) void gemm_direct(
    const float* __restrict__ x, const unsigned short* __restrict__ wt,
    unsigned short* __restrict__ h, int N)
{
    const int tid  = threadIdx.x;
    const int wave = tid >> 6, lane = tid & 63;
    const int g    = lane >> 4, l16 = lane & 15;
    const int m0   = blockIdx.x * 64 + wave * 16;

    const int row  = m0 + l16;                 // A row this lane feeds
    const int rowc = min(row, N - 1);          // clamp (junk discarded at write)

    const float*          xp = x  + (size_t)rowc * F_IN + g * 8;
    const unsigned short* bp = wt + (size_t)l16 * F_IN + g * 8;

    floatx4 acc[8];
    #pragma unroll
    for (int i = 0; i < 8; ++i) acc[i] = (floatx4)(0.f);

    #pragma unroll
    for (int kc = 0; kc < 16; ++kc) {
        const int k0 = kc * 32;
        float4 a0 = *(const float4*)(xp + k0);
        float4 a1 = *(const float4*)(xp + k0 + 4);
        union { unsigned u[4]; short8 v; } af;
        af.u[0] = pack2bf(a0.x, a0.y);
        af.u[1] = pack2bf(a0.z, a0.w);
        af.u[2] = pack2bf(a1.x, a1.y);
        af.u[3] = pack2bf(a1.z, a1.w);
        #pragma unroll
        for (int nt = 0; nt < 8; ++nt) {
            union { uint4 u; short8 v; } bf;
            bf.u = *(const uint4*)(bp + (size_t)nt * 16 * F_IN + k0);
            acc[nt] = __builtin_amdgcn_mfma_f32_16x16x32_bf16(af.v, bf.v, acc[nt], 0, 0, 0);
        }
    }

    // C/D layout: col = l16 (within n-tile), row = g*4 + r (within 16-row strip)
    #pragma unroll
    for (int nt = 0; nt < 8; ++nt) {
        #pragma unroll
        for (int r = 0; r < 4; ++r) {
            int orow = m0 + g * 4 + r;
            if (orow < N)
                h[(size_t)orow * F_OUT + nt * 16 + l16] = f2bf(acc[nt][r]);
        }
    }
}

// ---------------------------------------------------------------------------
// Partition 1: coarse histogram (bin = dst >> 7), LDS-aggregated.
// ---------------------------------------------------------------------------
__global__ __launch_bounds__(512) void coarse_hist(
    const int* __restrict__ ei, int* __restrict__ cnt, int E, int C)
{
    __shared__ int lh[CMAX];
    int tid = threadIdx.x;
    if (tid < CMAX) lh[tid] = 0;
    __syncthreads();
    int base = blockIdx.x * EPB;
    #pragma unroll
    for (int j = 0; j < EPB / 512; ++j) {
        int e = base + j * 512 + tid;
        if (e < E) atomicAdd(&lh[ei[E + e] >> 7], 1);
    }
    __syncthreads();
    if (tid < C && lh[tid] > 0) atomicAdd(&cnt[tid], lh[tid]);
}

// ---------------------------------------------------------------------------
// Partition 2 + w convert fused (grid = 1 + 128):
//   block 0      : exclusive scan of C (<=512) coarse bins -> binoff, cursor
//   blocks 1..128: w fp32 [512][128] -> wt bf16 [128][512]
// ---------------------------------------------------------------------------
__global__ __launch_bounds__(512) void scan_convert(
    const int* __restrict__ cnt, int* __restrict__ binoff,
    int* __restrict__ cursor, int C, int E,
    const float* __restrict__ w, unsigned short* __restrict__ wt)
{
    if (blockIdx.x > 0) {
        int gid = (blockIdx.x - 1) * 512 + threadIdx.x;   // 128*512 = 65536
        int n = gid >> 9, k = gid & 511;
        wt[gid] = f2bf(w[(size_t)k * F_OUT + n]);
        return;
    }
    __shared__ int s[CMAX];
    int tid = threadIdx.x;
    int v = (tid < C) ? cnt[tid] : 0;
    s[tid] = v;
    __syncthreads();
    #pragma unroll
    for (int off = 1; off < CMAX; off <<= 1) {
        int t = (tid >= off) ? s[tid - off] : 0;
        __syncthreads();
        s[tid] += t;
        __syncthreads();
    }
    if (tid < C) { int ex = s[tid] - v; binoff[tid] = ex; cursor[tid] = ex; }
    if (tid == 0) binoff[C] = E;
}

// ---------------------------------------------------------------------------
// Partition 3: coarse fill. Per block: LDS rank per edge + ONE batched
// cursor claim per bin -> ~10-entry contiguous runs (line-local).
// Outputs: k32 = {src u16 | bf16 w}, d8 = dst & 127.
// ---------------------------------------------------------------------------
__global__ __launch_bounds__(512) void coarse_fill(
    const int* __restrict__ ei, const float* __restrict__ ew,
    int* __restrict__ cursor, unsigned* __restrict__ k32,
    unsigned char* __restrict__ d8, int E, int C)
{
    __shared__ int lh[CMAX];
    __shared__ int lbase[CMAX];
    int tid = threadIdx.x;
    if (tid < CMAX) lh[tid] = 0;
    __syncthreads();

    const int base = blockIdx.x * EPB;
    unsigned       mykey[EPB / 512];
    unsigned char  mydl[EPB / 512];
    short          mybin[EPB / 512];
    unsigned short myrank[EPB / 512];

    #pragma unroll
    for (int j = 0; j < EPB / 512; ++j) {
        int e = base + j * 512 + tid;
        mybin[j] = -1;
        if (e < E) {
            int   src = ei[e];
            int   dst = ei[E + e];
            float w   = ew[e];
            int bin = dst >> 7;
            mykey[j]  = (unsigned)src | ((unsigned)f2bf(w) << 16);
            mydl[j]   = (unsigned char)(dst & (CB - 1));
            mybin[j]  = (short)bin;
            myrank[j] = (unsigned short)atomicAdd(&lh[bin], 1);
        }
    }
    __syncthreads();
    if (tid < C && lh[tid] > 0) lbase[tid] = atomicAdd(&cursor[tid], lh[tid]);
    __syncthreads();
    #pragma unroll
    for (int j = 0; j < EPB / 512; ++j) {
        if (mybin[j] >= 0) {
            int p = lbase[mybin[j]] + myrank[j];
            k32[p] = mykey[j];
            d8[p]  = mydl[j];
        }
    }
}

// ---------------------------------------------------------------------------
// Fused fine-sort + aggregate: one block per HALF coarse bucket (64 nodes)
// -> 782 blocks, all co-resident (17 KB LDS, 256 thr). Two streaming passes
// over the bucket's d8: (1) 64-bin hist, (2) place keys into sorted LDS.
// Phase B: wave per 16 nodes; half-wave per edge parity; lane = 4 feats via
// one uint2 gather; shfl_xor(32) reduce; fused bias+relu float4 writeout.
// ---------------------------------------------------------------------------
__global__ __launch_bounds__(256) void fine_agg(
    const unsigned short* __restrict__ h, const unsigned* __restrict__ k32,
    const unsigned char* __restrict__ d8, const int* __restrict__ binoff,
    const float* __restrict__ bias, float* __restrict__ out, int N)
{
    __shared__ unsigned ssort[CAP];          // 16 KB
    __shared__ int lh[64], lcur[64];
    __shared__ int sso[65];

    const int b     = blockIdx.x;
    const int cb    = b >> 1;                // coarse bucket
    const int hb    = b & 1;                 // which 64-node half
    const int tid   = threadIdx.x;
    const int start = binoff[cb];
    const int end   = binoff[cb + 1];
    const int wave  = tid >> 6;
    const int lane  = tid & 63;
    const int half  = lane >> 5;             // edge parity
    const int q     = lane & 31;             // feats q*4 .. q*4+3
    const float4 bv = *(const float4*)&bias[q * 4];

    if (tid < 64) lh[tid] = 0;
    __syncthreads();

    // pass 1: histogram of this half's nodes
    for (int i = start + tid; i < end; i += 256) {
        int d = d8[i];
        if ((d >> 6) == hb) atomicAdd(&lh[d & 63], 1);
    }
    __syncthreads();

    // exclusive scan of 64 counts (wave 0)
    if (wave == 0) {
        int v = lh[lane & 63];
        int orig = v;
        #pragma unroll
        for (int off = 1; off < 64; off <<= 1) {
            int t = __shfl_up(v, off);
            if (lane >= off) v += t;
        }
        sso[lane]  = v - orig;
        lcur[lane] = v - orig;
        if (lane == 63) sso[64] = v;
    }
    __syncthreads();
    const int hcnt = sso[64];

    if (hcnt <= CAP) {
        // pass 2: place keys into sorted LDS
        for (int i = start + tid; i < end; i += 256) {
            int d = d8[i];
            if ((d >> 6) == hb) {
                int r = atomicAdd(&lcur[d & 63], 1);
                ssort[r] = k32[i];
            }
        }
        __syncthreads();

        #pragma unroll 1
        for (int t = 0; t < 16; ++t) {
            int nd   = wave * 16 + t;
            int node = cb * CB + hb * 64 + nd;
            int s = sso[nd], e = sso[nd + 1];
            float4 acc = make_float4(0.f, 0.f, 0.f, 0.f);
            for (int i = s; i < e; i += 8) {
                #pragma unroll
                for (int j = 0; j < 4; ++j) {
                    int idx = i + j * 2 + half;
                    unsigned bk = 0;
                    if (idx < e) bk = ssort[idx];
                    float wgt = bf2f(bk >> 16);
                    uint2 hv = *(const uint2*)&h[(size_t)(bk & 0xFFFF) * F_OUT + q * 4];
                    acc.x += bf2f(hv.x & 0xFFFF) * wgt;
                    acc.y += bf2f(hv.x >> 16)    * wgt;
                    acc.z += bf2f(hv.y & 0xFFFF) * wgt;
                    acc.w += bf2f(hv.y >> 16)    * wgt;
                }
            }
            acc.x += __shfl_xor(acc.x, 32);
            acc.y += __shfl_xor(acc.y, 32);
            acc.z += __shfl_xor(acc.z, 32);
            acc.w += __shfl_xor(acc.w, 32);
            if (half == 0 && node < N) {
                float4 o;
                o.x = fmaxf(acc.x + bv.x, 0.f);
                o.y = fmaxf(acc.y + bv.y, 0.f);
                o.z = fmaxf(acc.z + bv.z, 0.f);
                o.w = fmaxf(acc.w + bv.w, 0.f);
                *(float4*)&out[(size_t)node * F_OUT + q * 4] = o;
            }
        }
    } else {
        // pathological half-bucket (> CAP edges): correct-but-slow path
        #pragma unroll 1
        for (int t = 0; t < 16; ++t) {
            int nd   = wave * 16 + t;
            int node = cb * CB + hb * 64 + nd;
            int want = hb * 64 + nd;
            float4 acc = make_float4(0.f, 0.f, 0.f, 0.f);
            for (int i = start; i < end; ++i) {
                if (d8[i] == (unsigned char)want) {
                    unsigned bk = k32[i];
                    float wgt = bf2f(bk >> 16);
                    uint2 hv = *(const uint2*)&h[(size_t)(bk & 0xFFFF) * F_OUT + q * 4];
                    acc.x += bf2f(hv.x & 0xFFFF) * wgt;
                    acc.y += bf2f(hv.x >> 16)    * wgt;
                    acc.z += bf2f(hv.y & 0xFFFF) * wgt;
                    acc.w += bf2f(hv.y >> 16)    * wgt;
                }
            }
            if (half == 0 && node < N) {
                float4 o;
                o.x = fmaxf(acc.x + bv.x, 0.f);
                o.y = fmaxf(acc.y + bv.y, 0.f);
                o.z = fmaxf(acc.z + bv.z, 0.f);
                o.w = fmaxf(acc.w + bv.w, 0.f);
                *(float4*)&out[(size_t)node * F_OUT + q * 4] = o;
            }
        }
    }
}

static inline size_t align256(size_t x) { return (x + 255) & ~(size_t)255; }

extern "C" void kernel_launch(void* const* d_in, const int* in_sizes, int n_in,
                              void* d_out, int out_size, void* d_ws, size_t ws_size,
                              hipStream_t stream)
{
    const float* x    = (const float*)d_in[0];   // [N, 512]
    const int*   ei   = (const int*)  d_in[1];   // [2, E] int32
    const float* ew   = (const float*)d_in[2];   // [E]
    const float* w    = (const float*)d_in[3];   // [512, 128]
    const float* bias = (const float*)d_in[4];   // [128]
    float*       out  = (float*)d_out;           // [N, 128]

    const int N = in_sizes[0] / F_IN;            // 50000
    const int E = in_sizes[2];                   // 1600000
    const int C = (N + CB - 1) / CB;             // 391 coarse buckets

    // workspace layout (~21.5 MB)
    char*  ws = (char*)d_ws;
    size_t off = 0;
    unsigned short* h      = (unsigned short*)(ws + off); off += align256((size_t)N * F_OUT * 2);
    unsigned short* wt     = (unsigned short*)(ws + off); off += align256((size_t)F_OUT * F_IN * 2);
    int*            cnt    = (int*)(ws + off);            off += align256((size_t)(C + 1) * 4);
    int*            binoff = (int*)(ws + off);            off += align256((size_t)(C + 1) * 4);
    int*            cursor = (int*)(ws + off);            off += align256((size_t)C * 4);
    unsigned*       k32    = (unsigned*)(ws + off);       off += align256((size_t)E * 4);
    unsigned char*  d8     = (unsigned char*)(ws + off);  off += align256((size_t)E);

    const int pblocks = (E + EPB - 1) / EPB;     // 391

    (void)hipMemsetAsync(cnt, 0, (size_t)C * 4, stream);
    coarse_hist<<<pblocks, 512, 0, stream>>>(ei, cnt, E, C);
    scan_convert<<<1 + (F_IN * F_OUT) / 512, 512, 0, stream>>>(cnt, binoff, cursor, C, E, w, wt);
    coarse_fill<<<pblocks, 512, 0, stream>>>(ei, ew, cursor, k32, d8, E, C);
    gemm_direct<<<(N + 63) / 64, 256, 0, stream>>>(x, wt, h, N);
    fine_agg<<<2 * C, 256, 0, stream>>>(h, k32, d8, binoff, bias, out, N);
}

// Round 9
// 271.613 us; speedup vs baseline: 1.1874x; 1.1874x over previous
//
#include <hip/hip_runtime.h>

#define F_IN  512
#define F_OUT 128
#define CB    128          // nodes per coarse bucket
#define EPB   4096         // edges per partition block
#define CMAX  512          // max coarse buckets (N <= 65536)
#define CAP   4096         // max edges per half-bucket in LDS (mean ~2048)

typedef __attribute__((ext_vector_type(8))) short  short8;
typedef __attribute__((ext_vector_type(4))) float  floatx4;

__device__ __forceinline__ unsigned short f2bf(float f) {
    unsigned u = __float_as_uint(f);
    return (unsigned short)((u + 0x7FFF + ((u >> 16) & 1)) >> 16);  // RNE
}
__device__ __forceinline__ float bf2f(unsigned b) {
    return __uint_as_float(b << 16);
}

// ---------------------------------------------------------------------------
// Kernel 1 (overlapped): blocks 0..FB-1 do the coarse dst histogram;
// blocks FB.. do w fp32 [512][128] -> wt bf16 [128][512].
// ---------------------------------------------------------------------------
__global__ __launch_bounds__(256) void hist_convert(
    const int* __restrict__ ei, int* __restrict__ cnt, int E, int C, int FB,
    const float* __restrict__ w, unsigned short* __restrict__ wt)
{
    const int tid = threadIdx.x;
    if ((int)blockIdx.x >= FB) {
        int cid = blockIdx.x - FB;                  // 0..127
        int g0  = cid * 512 + tid;
        #pragma unroll
        for (int r = 0; r < 2; ++r) {
            int gid = g0 + r * 256;
            int n = gid >> 9, k = gid & 511;
            wt[gid] = f2bf(w[(size_t)k * F_OUT + n]);
        }
        return;
    }
    __shared__ int lh[CMAX];
    lh[tid] = 0; lh[tid + 256] = 0;
    __syncthreads();
    int base = blockIdx.x * EPB;
    #pragma unroll
    for (int j = 0; j < EPB / 256; ++j) {
        int e = base + j * 256 + tid;
        if (e < E) atomicAdd(&lh[ei[E + e] >> 7], 1);
    }
    __syncthreads();
    if (tid < C && lh[tid] > 0) atomicAdd(&cnt[tid], lh[tid]);
    int t2 = tid + 256;
    if (t2 < C && lh[t2] > 0) atomicAdd(&cnt[t2], lh[t2]);
}

// ---------------------------------------------------------------------------
// Kernel 2: exclusive scan of C (<=512) coarse bins -> binoff, cursor.
// ---------------------------------------------------------------------------
__global__ __launch_bounds__(512) void scan_bins(
    const int* __restrict__ cnt, int* __restrict__ binoff,
    int* __restrict__ cursor, int C, int E)
{
    __shared__ int s[CMAX];
    int tid = threadIdx.x;
    int v = (tid < C) ? cnt[tid] : 0;
    s[tid] = v;
    __syncthreads();
    #pragma unroll
    for (int off = 1; off < CMAX; off <<= 1) {
        int t = (tid >= off) ? s[tid - off] : 0;
        __syncthreads();
        s[tid] += t;
        __syncthreads();
    }
    if (tid < C) { int ex = s[tid] - v; binoff[tid] = ex; cursor[tid] = ex; }
    if (tid == 0) binoff[C] = E;
}

// ---------------------------------------------------------------------------
// Kernel 3 (overlapped): blocks 0..FB-1 = coarse fill (memory-bound),
// blocks FB.. = MFMA GEMM (compute-bound). Independent work co-scheduled
// on the same CUs so the phase costs max(), not sum().
//
// Fill: LDS rank + ONE batched cursor claim per bin -> ~10-entry contiguous
// runs of 8-B entries {src u16 | bf16 w, dst&127} (line-local writes).
//
// GEMM: h[N,128](bf16) = x(fp32->bf16) @ wt. 64-row tile/block, BK=64,
// LDS stride 68, prefetch into regs across stages (R7-proven structure).
// ---------------------------------------------------------------------------
__global__ __launch_bounds__(256, 2) void fill_gemm(
    const int* __restrict__ ei, const float* __restrict__ ew,
    int* __restrict__ cursor, uint2* __restrict__ ent, int E, int C, int FB,
    const float* __restrict__ x, const unsigned short* __restrict__ wt,
    unsigned short* __restrict__ h, int N)
{
    const int tid = threadIdx.x;

    if ((int)blockIdx.x < FB) {
        // ----- coarse fill -----
        __shared__ int lh[CMAX];
        __shared__ int lbase[CMAX];
        lh[tid] = 0; lh[tid + 256] = 0;
        __syncthreads();

        const int base = blockIdx.x * EPB;
        unsigned       mykey[EPB / 256];
        unsigned char  mydl[EPB / 256];
        short          mybin[EPB / 256];
        unsigned short myrank[EPB / 256];

        #pragma unroll
        for (int j = 0; j < EPB / 256; ++j) {
            int e = base + j * 256 + tid;
            mybin[j] = -1;
            if (e < E) {
                int   src = ei[e];
                int   dst = ei[E + e];
                float w   = ew[e];
                int bin = dst >> 7;
                mykey[j]  = (unsigned)src | ((unsigned)f2bf(w) << 16);
                mydl[j]   = (unsigned char)(dst & (CB - 1));
                mybin[j]  = (short)bin;
                myrank[j] = (unsigned short)atomicAdd(&lh[bin], 1);
            }
        }
        __syncthreads();
        if (tid < C && lh[tid] > 0) lbase[tid] = atomicAdd(&cursor[tid], lh[tid]);
        int t2 = tid + 256;
        if (t2 < C && lh[t2] > 0) lbase[t2] = atomicAdd(&cursor[t2], lh[t2]);
        __syncthreads();
        #pragma unroll
        for (int j = 0; j < EPB / 256; ++j) {
            if (mybin[j] >= 0) {
                int p = lbase[mybin[j]] + myrank[j];
                ent[p] = make_uint2(mykey[j], mydl[j]);
            }
        }
        return;
    }

    // ----- GEMM -----
    __shared__ unsigned short sa[64 * 68];     // [row][k]
    __shared__ unsigned short sb[128 * 68];    // [n][k]

    const int wave = tid >> 6, lane = tid & 63;
    const int g    = lane >> 4, l16 = lane & 15;
    const int m0   = (blockIdx.x - FB) * 64;

    const int arow = tid >> 2, aq = tid & 3;
    const int brow = tid >> 1, bh = tid & 1;

    floatx4 acc[8];
    #pragma unroll
    for (int i = 0; i < 8; ++i) acc[i] = (floatx4)(0.f);

    const bool  avalid = (m0 + arow) < N;
    const float* xp = x + (size_t)(m0 + arow) * F_IN + aq * 16;
    const unsigned short* bp = wt + brow * F_IN + bh * 32;

    float4 ax[4];
    uint4  bv[4];
    #pragma unroll
    for (int i = 0; i < 4; ++i) ax[i] = make_float4(0.f, 0.f, 0.f, 0.f);
    if (avalid) {
        #pragma unroll
        for (int i = 0; i < 4; ++i) ax[i] = ((const float4*)xp)[i];
    }
    #pragma unroll
    for (int i = 0; i < 4; ++i) bv[i] = ((const uint4*)bp)[i];

    for (int s = 0; s < 8; ++s) {
        __syncthreads();
        #pragma unroll
        for (int i = 0; i < 4; ++i) {
            ushort4 t;
            t.x = f2bf(ax[i].x); t.y = f2bf(ax[i].y);
            t.z = f2bf(ax[i].z); t.w = f2bf(ax[i].w);
            *(ushort4*)&sa[arow * 68 + aq * 16 + i * 4] = t;
        }
        #pragma unroll
        for (int i = 0; i < 4; ++i) {
            *(uint2*)&sb[brow * 68 + bh * 32 + i * 8]     = make_uint2(bv[i].x, bv[i].y);
            *(uint2*)&sb[brow * 68 + bh * 32 + i * 8 + 4] = make_uint2(bv[i].z, bv[i].w);
        }
        if (s < 7) {
            int k0n = (s + 1) * 64;
            if (avalid) {
                #pragma unroll
                for (int i = 0; i < 4; ++i) ax[i] = ((const float4*)(xp + k0n))[i];
            }
            #pragma unroll
            for (int i = 0; i < 4; ++i) bv[i] = ((const uint4*)(bp + k0n))[i];
        }
        __syncthreads();

        #pragma unroll
        for (int kc = 0; kc < 2; ++kc) {
            union { ushort4 u[2]; short8 v; } af;
            int abase = (wave * 16 + l16) * 68 + kc * 32 + g * 8;
            af.u[0] = *(ushort4*)&sa[abase];
            af.u[1] = *(ushort4*)&sa[abase + 4];
            #pragma unroll
            for (int nt = 0; nt < 8; ++nt) {
                union { ushort4 u[2]; short8 v; } bf;
                int bbase = (nt * 16 + l16) * 68 + kc * 32 + g * 8;
                bf.u[0] = *(ushort4*)&sb[bbase];
                bf.u[1] = *(ushort4*)&sb[bbase + 4];
                acc[nt] = __builtin_amdgcn_mfma_f32_16x16x32_bf16(af.v, bf.v, acc[nt], 0, 0, 0);
            }
        }
    }

    #pragma unroll
    for (int nt = 0; nt < 8; ++nt) {
        #pragma unroll
        for (int r = 0; r < 4; ++r) {
            int row = m0 + wave * 16 + g * 4 + r;
            if (row < N) h[(size_t)row * F_OUT + nt * 16 + l16] = f2bf(acc[nt][r]);
        }
    }
}

// ---------------------------------------------------------------------------
// Kernel 4: fused fine-sort + aggregate, one block per HALF coarse bucket
// (64 nodes) -> 782 blocks. Two passes over the bucket's entries:
// (1) 64-bin hist, (2) place keys into node-sorted LDS. Then wave per 16
// nodes; half-wave per edge parity; lane = 4 feats (one uint2 gather);
// shfl_xor(32) reduce; fused bias+relu float4 writeout.
// ---------------------------------------------------------------------------
__global__ __launch_bounds__(256) void fine_agg(
    const unsigned short* __restrict__ h, const uint2* __restrict__ ent,
    const int* __restrict__ binoff, const float* __restrict__ bias,
    float* __restrict__ out, int N)
{
    __shared__ unsigned ssort[CAP];          // 16 KB
    __shared__ int lh[64], lcur[64];
    __shared__ int sso[65];

    const int b     = blockIdx.x;
    const int cb    = b >> 1;                // coarse bucket
    const int hb    = b & 1;                 // which 64-node half
    const int tid   = threadIdx.x;
    const int start = binoff[cb];
    const int end   = binoff[cb + 1];
    const int wave  = tid >> 6;
    const int lane  = tid & 63;
    const int half  = lane >> 5;             // edge parity
    const int q     = lane & 31;             // feats q*4 .. q*4+3
    const float4 bv = *(const float4*)&bias[q * 4];

    if (tid < 64) lh[tid] = 0;
    __syncthreads();

    for (int i = start + tid; i < end; i += 256) {
        int d = (int)ent[i].y;
        if ((d >> 6) == hb) atomicAdd(&lh[d & 63], 1);
    }
    __syncthreads();

    if (wave == 0) {
        int v = lh[lane & 63];
        int orig = v;
        #pragma unroll
        for (int off = 1; off < 64; off <<= 1) {
            int t = __shfl_up(v, off);
            if (lane >= off) v += t;
        }
        sso[lane]  = v - orig;
        lcur[lane] = v - orig;
        if (lane == 63) sso[64] = v;
    }
    __syncthreads();
    const int hcnt = sso[64];

    if (hcnt <= CAP) {
        for (int i = start + tid; i < end; i += 256) {
            uint2 e = ent[i];
            int d = (int)e.y;
            if ((d >> 6) == hb) {
                int r = atomicAdd(&lcur[d & 63], 1);
                ssort[r] = e.x;
            }
        }
        __syncthreads();

        #pragma unroll 1
        for (int t = 0; t < 16; ++t) {
            int nd   = wave * 16 + t;
            int node = cb * CB + hb * 64 + nd;
            int s = sso[nd], e = sso[nd + 1];
            float4 acc = make_float4(0.f, 0.f, 0.f, 0.f);
            for (int i = s; i < e; i += 8) {
                #pragma unroll
                for (int j = 0; j < 4; ++j) {
                    int idx = i + j * 2 + half;
                    unsigned bk = 0;
                    if (idx < e) bk = ssort[idx];
                    float wgt = bf2f(bk >> 16);
                    uint2 hv = *(const uint2*)&h[(size_t)(bk & 0xFFFF) * F_OUT + q * 4];
                    acc.x += bf2f(hv.x & 0xFFFF) * wgt;
                    acc.y += bf2f(hv.x >> 16)    * wgt;
                    acc.z += bf2f(hv.y & 0xFFFF) * wgt;
                    acc.w += bf2f(hv.y >> 16)    * wgt;
                }
            }
            acc.x += __shfl_xor(acc.x, 32);
            acc.y += __shfl_xor(acc.y, 32);
            acc.z += __shfl_xor(acc.z, 32);
            acc.w += __shfl_xor(acc.w, 32);
            if (half == 0 && node < N) {
                float4 o;
                o.x = fmaxf(acc.x + bv.x, 0.f);
                o.y = fmaxf(acc.y + bv.y, 0.f);
                o.z = fmaxf(acc.z + bv.z, 0.f);
                o.w = fmaxf(acc.w + bv.w, 0.f);
                *(float4*)&out[(size_t)node * F_OUT + q * 4] = o;
            }
        }
    } else {
        // pathological half-bucket (> CAP edges): correct-but-slow path
        #pragma unroll 1
        for (int t = 0; t < 16; ++t) {
            int nd   = wave * 16 + t;
            int node = cb * CB + hb * 64 + nd;
            int want = hb * 64 + nd;
            float4 acc = make_float4(0.f, 0.f, 0.f, 0.f);
            for (int i = start; i < end; ++i) {
                uint2 e = ent[i];
                if ((int)e.y == want) {
                    unsigned bk = e.x;
                    float wgt = bf2f(bk >> 16);
                    uint2 hv = *(const uint2*)&h[(size_t)(bk & 0xFFFF) * F_OUT + q * 4];
                    acc.x += bf2f(hv.x & 0xFFFF) * wgt;
                    acc.y += bf2f(hv.x >> 16)    * wgt;
                    acc.z += bf2f(hv.y & 0xFFFF) * wgt;
                    acc.w += bf2f(hv.y >> 16)    * wgt;
                }
            }
            if (half == 0 && node < N) {
                float4 o;
                o.x = fmaxf(acc.x + bv.x, 0.f);
                o.y = fmaxf(acc.y + bv.y, 0.f);
                o.z = fmaxf(acc.z + bv.z, 0.f);
                o.w = fmaxf(acc.w + bv.w, 0.f);
                *(float4*)&out[(size_t)node * F_OUT + q * 4] = o;
            }
        }
    }
}

static inline size_t align256(size_t x) { return (x + 255) & ~(size_t)255; }

extern "C" void kernel_launch(void* const* d_in, const int* in_sizes, int n_in,
                              void* d_out, int out_size, void* d_ws, size_t ws_size,
                              hipStream_t stream)
{
    const float* x    = (const float*)d_in[0];   // [N, 512]
    const int*   ei   = (const int*)  d_in[1];   // [2, E] int32
    const float* ew   = (const float*)d_in[2];   // [E]
    const float* w    = (const float*)d_in[3];   // [512, 128]
    const float* bias = (const float*)d_in[4];   // [128]
    float*       out  = (float*)d_out;           // [N, 128]

    const int N = in_sizes[0] / F_IN;            // 50000
    const int E = in_sizes[2];                   // 1600000
    const int C = (N + CB - 1) / CB;             // 391 coarse buckets

    // workspace layout (~26 MB)
    char*  ws = (char*)d_ws;
    size_t off = 0;
    unsigned short* h      = (unsigned short*)(ws + off); off += align256((size_t)N * F_OUT * 2);
    unsigned short* wt     = (unsigned short*)(ws + off); off += align256((size_t)F_OUT * F_IN * 2);
    int*            cnt    = (int*)(ws + off);            off += align256((size_t)(C + 1) * 4);
    int*            binoff = (int*)(ws + off);            off += align256((size_t)(C + 1) * 4);
    int*            cursor = (int*)(ws + off);            off += align256((size_t)C * 4);
    uint2*          ent    = (uint2*)(ws + off);          off += align256((size_t)E * 8);

    const int FB = (E + EPB - 1) / EPB;          // 391 partition blocks
    const int GB = (N + 63) / 64;                // 782 gemm blocks
    const int WB = (F_IN * F_OUT) / 512;         // 128 convert blocks

    (void)hipMemsetAsync(cnt, 0, (size_t)C * 4, stream);
    hist_convert<<<FB + WB, 256, 0, stream>>>(ei, cnt, E, C, FB, w, wt);
    scan_bins<<<1, 512, 0, stream>>>(cnt, binoff, cursor, C, E);
    fill_gemm<<<FB + GB, 256, 0, stream>>>(ei, ew, cursor, ent, E, C, FB,
                                           x, wt, h, N);
    fine_agg<<<2 * C, 256, 0, stream>>>(h, ent, binoff, bias, out, N);
}